// Round 4
// baseline (202.308 us; speedup 1.0000x reference)
//
#include <hip/hip_runtime.h>

// LSTMnetwork: 3 sequential stages of h = lstm_act(inp @ Wp^T + b)
// M=8192, K=1024, packed N=3072 (f-gate dropped: i,g,o only).
// BM=256 x BN=192, BK=64, 512 thr (2x4 waves), T2 xor-swizzle,
// FAT 2-phase K-tile (24 MFMA/phase), counted vmcnt (5/2, never 0 mid-loop),
// setprio, T1 XCD 8x8-rect swizzle.

typedef float f32x4 __attribute__((ext_vector_type(4)));
typedef short short8 __attribute__((ext_vector_type(8)));
typedef unsigned short u16;

#define NP 3072
#define MROWS 8192
#define KDIM 1024
#define BM 256
#define BN 192
#define BK 64
#define LDS_A_SZ (BM * BK * 2)      // 32768 per buffer
#define LDS_B_SZ (BN * BK * 2)      // 24576 per buffer
#define LDS_B_OFF (2 * LDS_A_SZ)    // 65536; total 114688 (112 KB)

__device__ __forceinline__ u16 f2bf(float f) {
  unsigned u = __float_as_uint(f);
  u += 0x7fffu + ((u >> 16) & 1u);   // RTNE
  return (u16)(u >> 16);
}
__device__ __forceinline__ float sigmoid_f(float x) {
  return 1.0f / (1.0f + __expf(-x));
}
__device__ __forceinline__ float tanh_f(float x) {
  float xc = fminf(fmaxf(x, -15.0f), 15.0f);
  float e = __expf(2.0f * xc);
  return (e - 1.0f) / (e + 1.0f);
}
__device__ __forceinline__ void gload_lds16(const void* g, void* l) {
  __builtin_amdgcn_global_load_lds((const __attribute__((address_space(1))) void*)g,
                                   (__attribute__((address_space(3))) void*)l,
                                   16, 0, 0);
}

// ---------------- pre-passes (unchanged, verified) ----------------

__global__ __launch_bounds__(256) void k_convert_x(const float* __restrict__ x,
                                                   u16* __restrict__ out) {
  int tid = blockIdx.x * 256 + threadIdx.x;
  const float4* src = (const float4*)x + (size_t)tid * 2;
  float4 v0 = src[0], v1 = src[1];
  union { u16 u[8]; uint4 v; } r;
  r.u[0] = f2bf(v0.x); r.u[1] = f2bf(v0.y); r.u[2] = f2bf(v0.z); r.u[3] = f2bf(v0.w);
  r.u[4] = f2bf(v1.x); r.u[5] = f2bf(v1.y); r.u[6] = f2bf(v1.z); r.u[7] = f2bf(v1.w);
  ((uint4*)out)[tid] = r.v;
}

__global__ __launch_bounds__(256) void k_pack_w(const float* __restrict__ Wih0,
                                                const float* __restrict__ Wih12,
                                                u16* __restrict__ P) {
  int tid = blockIdx.x * 256 + threadIdx.x;
  int s   = tid / (NP * 128);
  int rem = tid - s * (NP * 128);
  int p   = rem >> 7;
  int k8  = rem & 127;
  int hb = p / 48;
  int pr = p - hb * 48;
  int gs = pr >> 4;
  int hl = pr & 15;
  int hcol = hb * 16 + hl;
  int dir = hcol >> 9;
  int h   = hcol & 511;
  int og  = (gs == 0) ? 0 : (gs + 1);     // 0->i, 1->g, 2->o
  const float* src;
  if (s == 0)
    src = Wih0 + ((size_t)(dir * 2048 + og * 512 + h)) * 1024 + k8 * 8;
  else
    src = Wih12 + ((size_t)(((s - 1) * 2 + dir) * 2048 + og * 512 + h)) * 1024 + k8 * 8;
  float4 v0 = ((const float4*)src)[0];
  float4 v1 = ((const float4*)src)[1];
  union { u16 u[8]; uint4 v; } r;
  r.u[0] = f2bf(v0.x); r.u[1] = f2bf(v0.y); r.u[2] = f2bf(v0.z); r.u[3] = f2bf(v0.w);
  r.u[4] = f2bf(v1.x); r.u[5] = f2bf(v1.y); r.u[6] = f2bf(v1.z); r.u[7] = f2bf(v1.w);
  ((uint4*)P)[tid] = r.v;
}

__global__ __launch_bounds__(256) void k_pack_bias(const float* __restrict__ bih0,
                                                   const float* __restrict__ bhh0,
                                                   const float* __restrict__ bih12,
                                                   const float* __restrict__ bhh12,
                                                   float* __restrict__ pb) {
  int tid = blockIdx.x * 256 + threadIdx.x;
  if (tid >= 3 * NP) return;
  int s = tid / NP;
  int p = tid - s * NP;
  int hb = p / 48;
  int pr = p - hb * 48;
  int gs = pr >> 4;
  int hl = pr & 15;
  int hcol = hb * 16 + hl;
  int dir = hcol >> 9;
  int h   = hcol & 511;
  int og  = (gs == 0) ? 0 : (gs + 1);
  int j   = og * 512 + h;
  float v;
  if (s == 0) {
    int i = dir * 2048 + j;
    v = bih0[i] + bhh0[i];
  } else {
    int i = ((s - 1) * 2 + dir) * 2048 + j;
    v = bih12[i] + bhh12[i];
  }
  pb[tid] = v;
}

// ---------------- fused GEMM + LSTM activation ----------------

#define BAR()    __builtin_amdgcn_s_barrier()
#define SCHEDB() __builtin_amdgcn_sched_barrier(0)
#define WAITV(N) asm volatile("s_waitcnt vmcnt(" #N ")" ::: "memory")
#define MM(Macc, Aop, Bop) Macc = __builtin_amdgcn_mfma_f32_16x16x32_bf16(Aop, Bop, Macc, 0, 0, 0)

#define LDA(MQ, K32, M4, BUF) \
  (*(const short8*)(lds + ((K32) ? aK1 : aK0) + ((BUF) * LDS_A_SZ + (MQ) * 8192 + (M4) * 2048)))
#define LDB(N3, K32, BUF) \
  (*(const short8*)(lds + ((K32) ? bK1 : bK0) + ((BUF) * LDS_B_SZ + (N3) * 2048)))

// one staging round = 512 thr x 16B = 8KB = 64 rows; linear LDS dest,
// inverse-swizzled source octet (rule 21: both-sides-or-neither).
#define STAGE_B(RB, BUF, KT) \
  gload_lds16(srcB + (size_t)(RB) * 64 * KDIM + (size_t)(KT) * BK, \
              lds + LDS_B_OFF + (BUF) * LDS_B_SZ + (RB) * 8192 + t * 16)
#define STAGE_A(ROWB, BUF, KT) \
  gload_lds16(srcA + (size_t)(ROWB) * KDIM + (size_t)(KT) * BK, \
              lds + (BUF) * LDS_A_SZ + (ROWB) * 128 + t * 16)

// 12 MFMA: one M-half x 3 N-frags x one k32
#define MM12(MQ, AA0, AA1, AA2, AA3, BB0, BB1, BB2) \
  MM(acc[(MQ)*4+0][0], AA0, BB0); MM(acc[(MQ)*4+1][0], AA1, BB0); \
  MM(acc[(MQ)*4+2][0], AA2, BB0); MM(acc[(MQ)*4+3][0], AA3, BB0); \
  MM(acc[(MQ)*4+0][1], AA0, BB1); MM(acc[(MQ)*4+1][1], AA1, BB1); \
  MM(acc[(MQ)*4+2][1], AA2, BB1); MM(acc[(MQ)*4+3][1], AA3, BB1); \
  MM(acc[(MQ)*4+0][2], AA0, BB2); MM(acc[(MQ)*4+1][2], AA1, BB2); \
  MM(acc[(MQ)*4+2][2], AA2, BB2); MM(acc[(MQ)*4+3][2], AA3, BB2);

// One K-tile = 2 FAT phases (one per M-half, full K=64, 24 MFMA each).
// ds_read order within ph0: [a k0 x4, b k0 x3] then [a k1 x4, b k1 x3] so the
// compiler's partial lgkmcnt starts k0-MFMAs while k1 reads drain under them.
// Staging for KT+1: 5 units in ph0 (B0,B1,B2,A@0,A@128), 2 in ph1 (A@64,A@192).
// vmcnt ledger (steady): enter tile with 2 outstanding (A@64,A@192 of THIS
// tile); ph0 +5 -> 7; MID needs those 2 oldest -> WAITV(5); ph1 +2 -> 7;
// BOUNDARY needs the 5 -> WAITV(2). Only the final tile drains to 0.
#define TILE2(BUF, KT, DO_STAGE, LASTMID) \
  { \
    /* ph0: M-half 0, k0+k1 */ \
    a0 = LDA(0, 0, 0, BUF); a1 = LDA(0, 0, 1, BUF); a2 = LDA(0, 0, 2, BUF); a3 = LDA(0, 0, 3, BUF); \
    b00 = LDB(0, 0, BUF); b01 = LDB(1, 0, BUF); b02 = LDB(2, 0, BUF); \
    a4 = LDA(0, 1, 0, BUF); a5 = LDA(0, 1, 1, BUF); a6 = LDA(0, 1, 2, BUF); a7 = LDA(0, 1, 3, BUF); \
    b10 = LDB(0, 1, BUF); b11 = LDB(1, 1, BUF); b12 = LDB(2, 1, BUF); \
    if (DO_STAGE) { STAGE_B(0, (BUF)^1, (KT)+1); STAGE_B(1, (BUF)^1, (KT)+1); STAGE_B(2, (BUF)^1, (KT)+1); \
                    STAGE_A(0, (BUF)^1, (KT)+1); STAGE_A(128, (BUF)^1, (KT)+1); } \
    BAR(); \
    __builtin_amdgcn_s_setprio(1); \
    MM12(0, a0, a1, a2, a3, b00, b01, b02); \
    MM12(0, a4, a5, a6, a7, b10, b11, b12); \
    __builtin_amdgcn_s_setprio(0); \
    if (LASTMID) { WAITV(0); } else { WAITV(5); } \
    BAR(); SCHEDB(); \
    /* ph1: M-half 1, k0+k1 (reuse b regs) */ \
    a0 = LDA(1, 0, 0, BUF); a1 = LDA(1, 0, 1, BUF); a2 = LDA(1, 0, 2, BUF); a3 = LDA(1, 0, 3, BUF); \
    a4 = LDA(1, 1, 0, BUF); a5 = LDA(1, 1, 1, BUF); a6 = LDA(1, 1, 2, BUF); a7 = LDA(1, 1, 3, BUF); \
    if (DO_STAGE) { STAGE_A(64, (BUF)^1, (KT)+1); STAGE_A(192, (BUF)^1, (KT)+1); } \
    BAR(); \
    __builtin_amdgcn_s_setprio(1); \
    MM12(1, a0, a1, a2, a3, b00, b01, b02); \
    MM12(1, a4, a5, a6, a7, b10, b11, b12); \
    __builtin_amdgcn_s_setprio(0); \
    if (DO_STAGE) { WAITV(2); } \
    BAR(); SCHEDB(); \
  }

template <bool F32OUT>
__global__ __launch_bounds__(512, 2) void k_lstm_gemm8(const u16* __restrict__ A,
                                                       const u16* __restrict__ Bp,
                                                       const float* __restrict__ bias,
                                                       void* __restrict__ outp) {
  __shared__ __align__(16) char lds[114688];
  const int t    = threadIdx.x;
  const int lane = t & 63;
  const int w    = t >> 6;          // 0..7
  const int wr   = w >> 2;          // 0..1 (M half: 128 rows)
  const int wc   = w & 3;           // 0..3 (N quarter: 48 packed cols)
  const int r16  = lane & 15, kg = lane >> 4;

  // T1: bijective XCD swizzle. HW linear n -> XCD n%8. XCD c owns an 8x8 rect
  // (8 N-cols x 8 M-bands): per-XCD set = A 4MB + B 3MB.
  const int n_hw = blockIdx.y * gridDim.x + blockIdx.x;
  const int c    = n_hw & 7;
  const int wlc  = n_hw >> 3;
  const int bx   = (c & 1) * 8 + (wlc & 7);    // 0..15
  const int by   = (c >> 1) * 8 + (wlc >> 3);  // 0..31
  const int brow = by * BM;
  const int bn0  = bx * BN;

  // per-lane swizzled LDS read bases: slot = (k32*4+kg) ^ (row&7)
  const int sw    = r16 & 7;
  const int slot0 = kg ^ sw;
  const int aK0 = wr * 16384 + r16 * 128 + slot0 * 16;
  const int aK1 = wr * 16384 + r16 * 128 + (slot0 ^ 4) * 16;
  const int bK0 = LDS_B_OFF + (wc * 48 + r16) * 128 + slot0 * 16;
  const int bK1 = LDS_B_OFF + (wc * 48 + r16) * 128 + (slot0 ^ 4) * 16;

  // staging source (inverse-permuted octet within each 128B row)
  const int rr   = t >> 3;                          // 0..63
  const int koct = ((t & 7) ^ (rr & 7)) << 3;       // element offset
  const u16* srcA = A  + (size_t)(brow + rr) * KDIM + koct;
  const u16* srcB = Bp + (size_t)(bn0  + rr) * KDIM + koct;

  f32x4 acc[8][3];
#pragma unroll
  for (int m = 0; m < 8; ++m)
#pragma unroll
    for (int n = 0; n < 3; ++n) acc[m][n] = (f32x4){0.f, 0.f, 0.f, 0.f};

  short8 a0, a1, a2, a3, a4, a5, a6, a7, b00, b01, b02, b10, b11, b12;

  // prologue: stage tile 0; WAITV(2) leaves A@64,A@192 outstanding -> matches
  // steady-state tile entry.
  STAGE_B(0, 0, 0); STAGE_B(1, 0, 0); STAGE_B(2, 0, 0);
  STAGE_A(0, 0, 0); STAGE_A(128, 0, 0);
  STAGE_A(64, 0, 0); STAGE_A(192, 0, 0);
  WAITV(2);
  BAR(); SCHEDB();

  for (int k2 = 0; k2 < 7; ++k2) {
    int kt = k2 * 2;
    TILE2(0, kt, 1, 0);
    TILE2(1, kt + 1, 1, 0);
  }
  TILE2(0, 14, 1, 0);
  TILE2(1, 15, 0, 1);

  // epilogue: lane holds i,g,o (n3=0,1,2) for hcol; rows per acc reg.
  {
    int pb = bn0 + wc * 48;
    float biV = bias[pb + r16];
    float bgV = bias[pb + 16 + r16];
    float boV = bias[pb + 32 + r16];
    int hcol = (bx * 4 + wc) * 16 + r16;
#pragma unroll
    for (int m8 = 0; m8 < 8; ++m8) {
      int rowb = brow + wr * 128 + (m8 >> 2) * 64 + (m8 & 3) * 16 + kg * 4;
#pragma unroll
      for (int r = 0; r < 4; ++r) {
        float vi = acc[m8][0][r] + biV;
        float vg = acc[m8][1][r] + bgV;
        float vo = acc[m8][2][r] + boV;
        float c2 = sigmoid_f(vi) * tanh_f(vg);
        float hv = sigmoid_f(vo) * tanh_f(c2);
        size_t oidx = (size_t)(rowb + r) * 1024 + hcol;
        if (F32OUT) ((float*)outp)[oidx] = hv;
        else        ((u16*)outp)[oidx]   = f2bf(hv);
      }
    }
  }
}

// ---------------- launch ----------------
extern "C" void kernel_launch(void* const* d_in, const int* in_sizes, int n_in,
                              void* d_out, int out_size, void* d_ws, size_t ws_size,
                              hipStream_t stream) {
  const float* x     = (const float*)d_in[0];
  const float* Wih0  = (const float*)d_in[1];
  const float* bih0  = (const float*)d_in[3];
  const float* bhh0  = (const float*)d_in[4];
  const float* Wih12 = (const float*)d_in[5];
  const float* bih12 = (const float*)d_in[7];
  const float* bhh12 = (const float*)d_in[8];

  char* ws = (char*)d_ws;
  u16*   xbf = (u16*)ws;                       // 16,777,216 B
  u16*   h1  = (u16*)(ws + 16777216);          // 16,777,216 B
  u16*   h2  = (u16*)(ws + 33554432);          // 16,777,216 B
  u16*   P3  = (u16*)(ws + 50331648);          // 18,874,368 B
  float* pb3 = (float*)(ws + 69206016);        // 36,864 B

  k_convert_x<<<4096, 256, 0, stream>>>(x, xbf);
  k_pack_w<<<4608, 256, 0, stream>>>(Wih0, Wih12, P3);
  k_pack_bias<<<36, 256, 0, stream>>>(bih0, bhh0, bih12, bhh12, pb3);

  dim3 grid(NP / BN, MROWS / BM);   // (16, 32) = 512 blocks = 2 exact CU rounds
  k_lstm_gemm8<false><<<grid, 512, 0, stream>>>(xbf, P3, pb3, h1);
  k_lstm_gemm8<false><<<grid, 512, 0, stream>>>(h1, P3 + (size_t)NP * KDIM, pb3 + NP, h2);
  k_lstm_gemm8<true ><<<grid, 512, 0, stream>>>(h2, P3 + (size_t)2 * NP * KDIM, pb3 + 2 * NP, d_out);
}

// Round 5
// 197.319 us; speedup vs baseline: 1.0253x; 1.0253x over previous
//
#include <hip/hip_runtime.h>

// LSTMnetwork: 3 sequential stages of h = lstm_act(inp @ Wp^T + b)
// M=8192, K=1024, packed N=3072 (f-gate dropped: i,g,o only).
// BM=256 x BN=192, BK=64, 512 thr (2x4 waves), T2 xor-swizzle,
// ONE barrier per K-tile (wave-skew overlap of LDS pipe and matrix pipe),
// full-tile prefetch distance (WAITV(0) is cheap), T1 XCD 8x8-rect swizzle.

typedef float f32x4 __attribute__((ext_vector_type(4)));
typedef short short8 __attribute__((ext_vector_type(8)));
typedef unsigned short u16;

#define NP 3072
#define MROWS 8192
#define KDIM 1024
#define BM 256
#define BN 192
#define BK 64
#define LDS_A_SZ (BM * BK * 2)      // 32768 per buffer
#define LDS_B_SZ (BN * BK * 2)      // 24576 per buffer
#define LDS_B_OFF (2 * LDS_A_SZ)    // 65536; total 114688 (112 KB)

__device__ __forceinline__ u16 f2bf(float f) {
  unsigned u = __float_as_uint(f);
  u += 0x7fffu + ((u >> 16) & 1u);   // RTNE
  return (u16)(u >> 16);
}
__device__ __forceinline__ float sigmoid_f(float x) {
  return 1.0f / (1.0f + __expf(-x));
}
__device__ __forceinline__ float tanh_f(float x) {
  float xc = fminf(fmaxf(x, -15.0f), 15.0f);
  float e = __expf(2.0f * xc);
  return (e - 1.0f) / (e + 1.0f);
}
__device__ __forceinline__ void gload_lds16(const void* g, void* l) {
  __builtin_amdgcn_global_load_lds((const __attribute__((address_space(1))) void*)g,
                                   (__attribute__((address_space(3))) void*)l,
                                   16, 0, 0);
}

// ---------------- pre-passes (unchanged, verified) ----------------

__global__ __launch_bounds__(256) void k_convert_x(const float* __restrict__ x,
                                                   u16* __restrict__ out) {
  int tid = blockIdx.x * 256 + threadIdx.x;
  const float4* src = (const float4*)x + (size_t)tid * 2;
  float4 v0 = src[0], v1 = src[1];
  union { u16 u[8]; uint4 v; } r;
  r.u[0] = f2bf(v0.x); r.u[1] = f2bf(v0.y); r.u[2] = f2bf(v0.z); r.u[3] = f2bf(v0.w);
  r.u[4] = f2bf(v1.x); r.u[5] = f2bf(v1.y); r.u[6] = f2bf(v1.z); r.u[7] = f2bf(v1.w);
  ((uint4*)out)[tid] = r.v;
}

__global__ __launch_bounds__(256) void k_pack_w(const float* __restrict__ Wih0,
                                                const float* __restrict__ Wih12,
                                                u16* __restrict__ P) {
  int tid = blockIdx.x * 256 + threadIdx.x;
  int s   = tid / (NP * 128);
  int rem = tid - s * (NP * 128);
  int p   = rem >> 7;
  int k8  = rem & 127;
  int hb = p / 48;
  int pr = p - hb * 48;
  int gs = pr >> 4;
  int hl = pr & 15;
  int hcol = hb * 16 + hl;
  int dir = hcol >> 9;
  int h   = hcol & 511;
  int og  = (gs == 0) ? 0 : (gs + 1);     // 0->i, 1->g, 2->o
  const float* src;
  if (s == 0)
    src = Wih0 + ((size_t)(dir * 2048 + og * 512 + h)) * 1024 + k8 * 8;
  else
    src = Wih12 + ((size_t)(((s - 1) * 2 + dir) * 2048 + og * 512 + h)) * 1024 + k8 * 8;
  float4 v0 = ((const float4*)src)[0];
  float4 v1 = ((const float4*)src)[1];
  union { u16 u[8]; uint4 v; } r;
  r.u[0] = f2bf(v0.x); r.u[1] = f2bf(v0.y); r.u[2] = f2bf(v0.z); r.u[3] = f2bf(v0.w);
  r.u[4] = f2bf(v1.x); r.u[5] = f2bf(v1.y); r.u[6] = f2bf(v1.z); r.u[7] = f2bf(v1.w);
  ((uint4*)P)[tid] = r.v;
}

__global__ __launch_bounds__(256) void k_pack_bias(const float* __restrict__ bih0,
                                                   const float* __restrict__ bhh0,
                                                   const float* __restrict__ bih12,
                                                   const float* __restrict__ bhh12,
                                                   float* __restrict__ pb) {
  int tid = blockIdx.x * 256 + threadIdx.x;
  if (tid >= 3 * NP) return;
  int s = tid / NP;
  int p = tid - s * NP;
  int hb = p / 48;
  int pr = p - hb * 48;
  int gs = pr >> 4;
  int hl = pr & 15;
  int hcol = hb * 16 + hl;
  int dir = hcol >> 9;
  int h   = hcol & 511;
  int og  = (gs == 0) ? 0 : (gs + 1);
  int j   = og * 512 + h;
  float v;
  if (s == 0) {
    int i = dir * 2048 + j;
    v = bih0[i] + bhh0[i];
  } else {
    int i = ((s - 1) * 2 + dir) * 2048 + j;
    v = bih12[i] + bhh12[i];
  }
  pb[tid] = v;
}

// ---------------- fused GEMM + LSTM activation ----------------

#define BAR()    __builtin_amdgcn_s_barrier()
#define SCHEDB() __builtin_amdgcn_sched_barrier(0)
#define WAITV(N) asm volatile("s_waitcnt vmcnt(" #N ")" ::: "memory")
#define MM(Macc, Aop, Bop) Macc = __builtin_amdgcn_mfma_f32_16x16x32_bf16(Aop, Bop, Macc, 0, 0, 0)

#define LDA(MQ, K32, M4, BUF) \
  (*(const short8*)(lds + ((K32) ? aK1 : aK0) + ((BUF) * LDS_A_SZ + (MQ) * 8192 + (M4) * 2048)))
#define LDB(N3, K32, BUF) \
  (*(const short8*)(lds + ((K32) ? bK1 : bK0) + ((BUF) * LDS_B_SZ + (N3) * 2048)))

// one staging round = 512 thr x 16B = 8KB = 64 rows; linear LDS dest,
// inverse-swizzled source octet (rule 21: both-sides-or-neither).
#define STAGE_B(RB, BUF, KT) \
  gload_lds16(srcB + (size_t)(RB) * 64 * KDIM + (size_t)(KT) * BK, \
              lds + LDS_B_OFF + (BUF) * LDS_B_SZ + (RB) * 8192 + t * 16)
#define STAGE_A(ROWB, BUF, KT) \
  gload_lds16(srcA + (size_t)(ROWB) * KDIM + (size_t)(KT) * BK, \
              lds + (BUF) * LDS_A_SZ + (ROWB) * 128 + t * 16)

// 12 MFMA: one M-half x 3 N-frags x one k32
#define MM12(MQ, AA0, AA1, AA2, AA3, BB0, BB1, BB2) \
  MM(acc[(MQ)*4+0][0], AA0, BB0); MM(acc[(MQ)*4+1][0], AA1, BB0); \
  MM(acc[(MQ)*4+2][0], AA2, BB0); MM(acc[(MQ)*4+3][0], AA3, BB0); \
  MM(acc[(MQ)*4+0][1], AA0, BB1); MM(acc[(MQ)*4+1][1], AA1, BB1); \
  MM(acc[(MQ)*4+2][1], AA2, BB1); MM(acc[(MQ)*4+3][1], AA3, BB1); \
  MM(acc[(MQ)*4+0][2], AA0, BB2); MM(acc[(MQ)*4+1][2], AA1, BB2); \
  MM(acc[(MQ)*4+2][2], AA2, BB2); MM(acc[(MQ)*4+3][2], AA3, BB2);

// One K-tile, ONE barrier. Wave program: issue 7 staging (vm) for kt+1 ->
// issue all 22 ds_reads (ordered so compiler's partial lgkmcnt drains them
// progressively under the MFMAs) -> 48 MFMA -> WAITV(0) (staging issued a
// full tile ago; L2 latency long past) -> s_barrier. No intra-tile barriers:
// waves skew, so one wave's ds_reads run under another's MFMAs (LDS pipe and
// matrix pipe overlap). Cross-wave LDS hazards only exist at the buffer swap,
// which the boundary WAITV(0)+BAR covers (per-wave lgkm drained by MFMA use).
#define TILE1(BUF, KT, DO_STAGE) \
  { \
    if (DO_STAGE) { STAGE_B(0, (BUF)^1, (KT)+1); STAGE_B(1, (BUF)^1, (KT)+1); STAGE_B(2, (BUF)^1, (KT)+1); \
                    STAGE_A(0, (BUF)^1, (KT)+1); STAGE_A(128, (BUF)^1, (KT)+1); \
                    STAGE_A(64, (BUF)^1, (KT)+1); STAGE_A(192, (BUF)^1, (KT)+1); } \
    SCHEDB(); \
    a0 = LDA(0, 0, 0, BUF); a1 = LDA(0, 0, 1, BUF); a2 = LDA(0, 0, 2, BUF); a3 = LDA(0, 0, 3, BUF); \
    b00 = LDB(0, 0, BUF); b01 = LDB(1, 0, BUF); b02 = LDB(2, 0, BUF); \
    a8 = LDA(1, 0, 0, BUF); a9 = LDA(1, 0, 1, BUF); aA = LDA(1, 0, 2, BUF); aB = LDA(1, 0, 3, BUF); \
    a4 = LDA(0, 1, 0, BUF); a5 = LDA(0, 1, 1, BUF); a6 = LDA(0, 1, 2, BUF); a7 = LDA(0, 1, 3, BUF); \
    b10 = LDB(0, 1, BUF); b11 = LDB(1, 1, BUF); b12 = LDB(2, 1, BUF); \
    aC = LDA(1, 1, 0, BUF); aD = LDA(1, 1, 1, BUF); aE = LDA(1, 1, 2, BUF); aF = LDA(1, 1, 3, BUF); \
    __builtin_amdgcn_s_setprio(1); \
    MM12(0, a0, a1, a2, a3, b00, b01, b02); \
    MM12(1, a8, a9, aA, aB, b00, b01, b02); \
    MM12(0, a4, a5, a6, a7, b10, b11, b12); \
    MM12(1, aC, aD, aE, aF, b10, b11, b12); \
    __builtin_amdgcn_s_setprio(0); \
    WAITV(0); \
    BAR(); SCHEDB(); \
  }

template <bool F32OUT>
__global__ __launch_bounds__(512, 2) void k_lstm_gemm8(const u16* __restrict__ A,
                                                       const u16* __restrict__ Bp,
                                                       const float* __restrict__ bias,
                                                       void* __restrict__ outp) {
  __shared__ __align__(16) char lds[114688];
  const int t    = threadIdx.x;
  const int lane = t & 63;
  const int w    = t >> 6;          // 0..7
  const int wr   = w >> 2;          // 0..1 (M half: 128 rows)
  const int wc   = w & 3;           // 0..3 (N quarter: 48 packed cols)
  const int r16  = lane & 15, kg = lane >> 4;

  // T1: bijective XCD swizzle. HW linear n -> XCD n%8. XCD c owns an 8x8 rect
  // (8 N-cols x 8 M-bands): per-XCD set = A 4MB + B 3MB.
  const int n_hw = blockIdx.y * gridDim.x + blockIdx.x;
  const int c    = n_hw & 7;
  const int wlc  = n_hw >> 3;
  const int bx   = (c & 1) * 8 + (wlc & 7);    // 0..15
  const int by   = (c >> 1) * 8 + (wlc >> 3);  // 0..31
  const int brow = by * BM;
  const int bn0  = bx * BN;

  // per-lane swizzled LDS read bases: slot = (k32*4+kg) ^ (row&7)
  const int sw    = r16 & 7;
  const int slot0 = kg ^ sw;
  const int aK0 = wr * 16384 + r16 * 128 + slot0 * 16;
  const int aK1 = wr * 16384 + r16 * 128 + (slot0 ^ 4) * 16;
  const int bK0 = LDS_B_OFF + (wc * 48 + r16) * 128 + slot0 * 16;
  const int bK1 = LDS_B_OFF + (wc * 48 + r16) * 128 + (slot0 ^ 4) * 16;

  // staging source (inverse-permuted octet within each 128B row)
  const int rr   = t >> 3;                          // 0..63
  const int koct = ((t & 7) ^ (rr & 7)) << 3;       // element offset
  const u16* srcA = A  + (size_t)(brow + rr) * KDIM + koct;
  const u16* srcB = Bp + (size_t)(bn0  + rr) * KDIM + koct;

  f32x4 acc[8][3];
#pragma unroll
  for (int m = 0; m < 8; ++m)
#pragma unroll
    for (int n = 0; n < 3; ++n) acc[m][n] = (f32x4){0.f, 0.f, 0.f, 0.f};

  short8 a0, a1, a2, a3, a4, a5, a6, a7, a8, a9, aA, aB, aC, aD, aE, aF;
  short8 b00, b01, b02, b10, b11, b12;

  // prologue: stage tile 0, drain, barrier.
  STAGE_B(0, 0, 0); STAGE_B(1, 0, 0); STAGE_B(2, 0, 0);
  STAGE_A(0, 0, 0); STAGE_A(128, 0, 0);
  STAGE_A(64, 0, 0); STAGE_A(192, 0, 0);
  WAITV(0);
  BAR(); SCHEDB();

  for (int k2 = 0; k2 < 7; ++k2) {
    int kt = k2 * 2;
    TILE1(0, kt, 1);
    TILE1(1, kt + 1, 1);
  }
  TILE1(0, 14, 1);
  TILE1(1, 15, 0);

  // epilogue: lane holds i,g,o (n3=0,1,2) for hcol; rows per acc reg.
  {
    int pb = bn0 + wc * 48;
    float biV = bias[pb + r16];
    float bgV = bias[pb + 16 + r16];
    float boV = bias[pb + 32 + r16];
    int hcol = (bx * 4 + wc) * 16 + r16;
#pragma unroll
    for (int m8 = 0; m8 < 8; ++m8) {
      int rowb = brow + wr * 128 + (m8 >> 2) * 64 + (m8 & 3) * 16 + kg * 4;
#pragma unroll
      for (int r = 0; r < 4; ++r) {
        float vi = acc[m8][0][r] + biV;
        float vg = acc[m8][1][r] + bgV;
        float vo = acc[m8][2][r] + boV;
        float c2 = sigmoid_f(vi) * tanh_f(vg);
        float hv = sigmoid_f(vo) * tanh_f(c2);
        size_t oidx = (size_t)(rowb + r) * 1024 + hcol;
        if (F32OUT) ((float*)outp)[oidx] = hv;
        else        ((u16*)outp)[oidx]   = f2bf(hv);
      }
    }
  }
}

// ---------------- launch ----------------
extern "C" void kernel_launch(void* const* d_in, const int* in_sizes, int n_in,
                              void* d_out, int out_size, void* d_ws, size_t ws_size,
                              hipStream_t stream) {
  const float* x     = (const float*)d_in[0];
  const float* Wih0  = (const float*)d_in[1];
  const float* bih0  = (const float*)d_in[3];
  const float* bhh0  = (const float*)d_in[4];
  const float* Wih12 = (const float*)d_in[5];
  const float* bih12 = (const float*)d_in[7];
  const float* bhh12 = (const float*)d_in[8];

  char* ws = (char*)d_ws;
  u16*   xbf = (u16*)ws;                       // 16,777,216 B
  u16*   h1  = (u16*)(ws + 16777216);          // 16,777,216 B
  u16*   h2  = (u16*)(ws + 33554432);          // 16,777,216 B
  u16*   P3  = (u16*)(ws + 50331648);          // 18,874,368 B
  float* pb3 = (float*)(ws + 69206016);        // 36,864 B

  k_convert_x<<<4096, 256, 0, stream>>>(x, xbf);
  k_pack_w<<<4608, 256, 0, stream>>>(Wih0, Wih12, P3);
  k_pack_bias<<<36, 256, 0, stream>>>(bih0, bhh0, bih12, bhh12, pb3);

  dim3 grid(NP / BN, MROWS / BM);   // (16, 32) = 512 blocks = 2 exact CU rounds
  k_lstm_gemm8<false><<<grid, 512, 0, stream>>>(xbf, P3, pb3, h1);
  k_lstm_gemm8<false><<<grid, 512, 0, stream>>>(h1, P3 + (size_t)NP * KDIM, pb3 + NP, h2);
  k_lstm_gemm8<true ><<<grid, 512, 0, stream>>>(h2, P3 + (size_t)2 * NP * KDIM, pb3 + 2 * NP, d_out);
}